// Round 20
// baseline (778.602 us; speedup 1.0000x reference)
//
#include <hip/hip_runtime.h>
#include <hip/hip_bf16.h>

typedef unsigned int u32;
typedef unsigned short u16;
typedef __attribute__((ext_vector_type(4))) float f32x4;
typedef __attribute__((ext_vector_type(8))) short s16x8;
typedef __attribute__((ext_vector_type(4))) u16 u16x4;
typedef __attribute__((ext_vector_type(8))) u16 u16x8;

#define DEVFN __device__ __forceinline__

DEVFN u16 f2bf(float f) {
  u32 x = __builtin_bit_cast(u32, f);
  u32 r = x + 0x7fffu + ((x >> 16) & 1u);   // round-to-nearest-even
  return (u16)(r >> 16);
}

DEVFN float bf2f(u16 b) { return __builtin_bit_cast(float, (u32)b << 16); }

DEVFN void gload_lds16(const u16* g, u16* l) {
  __builtin_amdgcn_global_load_lds((const __attribute__((address_space(1))) u32*)g,
                                   (__attribute__((address_space(3))) u32*)l, 16, 0, 0);
}

// ===========================================================================
// 256x256-tile 8-wave bf16 GEMM — 2-SLOT / 64KB LDS for 2 blocks/CU.
// ROUND-18 RETRY with the register pin FIXED: launch_bounds(512,2) keeps the
// VGPR budget at 256 (allocator uses 128 as in the 4-slot form); occupancy is
// then resource-driven: LDS 64KB -> 2 blocks/CU; VGPR pool (16 waves @128)
// -> 2 x 8-wave blocks. Cross-block MFMA overlap (m114) covers the shortened
// prefetch lead. Schedule correctness was validated in round 18 (absmax OK).
// Phase q: [vmcnt(0) | barrier | stage g_{q+1} -> slot (q+1)&1 |
//           read slot q&1 | 32 MFMA].
// ===========================================================================
#define KQV_PHASE(Q, DOSTAGE)                                                  \
  {                                                                            \
    asm volatile("s_waitcnt vmcnt(0)" ::: "memory");                           \
    __builtin_amdgcn_s_barrier();                                              \
    if (DOSTAGE) {                                                             \
      const int g_ = (Q) + 1;                                                  \
      const int sl_ = (g_ & 1) * 8192;                                         \
      const int k0_ = (g_ >> 1) * 64 + (g_ & 1) * 32;                          \
      gload_lds16(aS0 + k0_, smemw + sl_ + ldst);                              \
      gload_lds16(aS1 + k0_, smemw + sl_ + 4096 + ldst);                       \
      gload_lds16(bS0 + k0_, smemw + 16384 + sl_ + ldst);                      \
      gload_lds16(bS1 + k0_, smemw + 16384 + sl_ + 4096 + ldst);               \
    }                                                                          \
    {                                                                          \
      const int sl_ = ((Q) & 1) * 8192;                                        \
      const u16* As_ = smem + sl_;                                             \
      const u16* Bs_ = smem + 16384 + sl_;                                     \
      s16x8 fa_[8], fb_[4];                                                    \
      _Pragma("unroll") for (int mf = 0; mf < 8; ++mf)                         \
          fa_[mf] = *(const s16x8*)(As_ + baseA + mf * 512);                   \
      _Pragma("unroll") for (int nf = 0; nf < 4; ++nf)                         \
          fb_[nf] = *(const s16x8*)(Bs_ + baseB + nf * 512);                   \
      __builtin_amdgcn_s_setprio(1);                                           \
      _Pragma("unroll") for (int mf = 0; mf < 8; ++mf)                         \
        _Pragma("unroll") for (int nf = 0; nf < 4; ++nf)                       \
          acc[mf][nf] = __builtin_amdgcn_mfma_f32_16x16x32_bf16(               \
              fa_[mf], fb_[nf], acc[mf][nf], 0, 0, 0);                         \
      __builtin_amdgcn_s_setprio(0);                                           \
    }                                                                          \
    __builtin_amdgcn_sched_barrier(0);                                         \
  }

template<int RELU>
__launch_bounds__(512, 2)
__global__ void gemm256(const u16* __restrict__ Ag, int lda,
                        const u16* __restrict__ Bg, int ldb,
                        u16* __restrict__ C, int ldc,
                        const float* __restrict__ bias,
                        int M, int K, int ntiles) {
  extern __shared__ u16 smem_dyn[];
  const u16* smem = smem_dyn;
  u16* smemw = smem_dyn;

  const int tid = threadIdx.x;
  const int lane = tid & 63, wave = tid >> 6;
  const int wm = wave >> 2, wn = wave & 3;          // 2 (M) x 4 (N) waves
  const int l15 = lane & 15, l4 = lane >> 4;

  // bijective XCD-aware swizzle (m204)
  const int nwg = gridDim.x;
  const int q8 = nwg >> 3, r8 = nwg & 7;
  const int xcd = blockIdx.x & 7, io = blockIdx.x >> 3;
  const int wg = (xcd < r8) ? (xcd * (q8 + 1) + io)
                            : (r8 * (q8 + 1) + (xcd - r8) * q8 + io);
  const int m0 = (wg / ntiles) * 256, n0 = (wg % ntiles) * 256;

  const int chunkSwz = (l4 ^ ((l15 >> 1) & 3)) * 8;
  const int baseA = (wm * 128 + l15) * 32 + chunkSwz;
  const int baseB = (wn * 64 + l15) * 32 + chunkSwz;

  const int srow = tid >> 2;
  const int scol = (((tid & 3) ^ ((tid >> 3) & 3))) * 8;
  long ar0 = m0 + srow;        if (ar0 > M - 1) ar0 = M - 1;
  long ar1 = m0 + 128 + srow;  if (ar1 > M - 1) ar1 = M - 1;
  const u16* aS0 = Ag + ar0 * (long)lda + scol;
  const u16* aS1 = Ag + ar1 * (long)lda + scol;
  const u16* bS0 = Bg + (long)(n0 + srow) * ldb + scol;
  const u16* bS1 = Bg + (long)(n0 + 128 + srow) * ldb + scol;
  const int ldst = tid * 8;                       // u16 offset (16B per thread)

  f32x4 acc[8][4];
#pragma unroll
  for (int i = 0; i < 8; ++i)
#pragma unroll
    for (int j = 0; j < 4; ++j) acc[i][j] = (f32x4){0.f, 0.f, 0.f, 0.f};

  const int NT = K >> 6;                          // K-tiles (needs NT>=1)

  // prologue: stage group 0 (slot 0)
  {
    gload_lds16(aS0, smemw + ldst);
    gload_lds16(aS1, smemw + 4096 + ldst);
    gload_lds16(bS0, smemw + 16384 + ldst);
    gload_lds16(bS1, smemw + 16384 + 4096 + ldst);
    __builtin_amdgcn_sched_barrier(0);
  }

  for (int t = 0; t < NT - 1; ++t) {
    KQV_PHASE(2 * t,     true);
    KQV_PHASE(2 * t + 1, true);
  }
  KQV_PHASE(2 * NT - 2, true);     // stages last group (2NT-1)
  KQV_PHASE(2 * NT - 1, false);

  // epilogue: C/D map col=lane&15, row=4*(lane>>4)+reg
#pragma unroll
  for (int mf = 0; mf < 8; ++mf) {
#pragma unroll
    for (int nf = 0; nf < 4; ++nf) {
      const int n = n0 + wn * 64 + nf * 16 + l15;
      const float bv = bias[n];
#pragma unroll
      for (int r = 0; r < 4; ++r) {
        const int s = wm * 128 + mf * 16 + l4 * 4 + r;
        if (m0 + s >= M) continue;
        float v = acc[mf][nf][r] + bv;
        if (RELU) v = v > 0.f ? v : 0.f;
        C[(long)(m0 + s) * ldc + n] = f2bf(v);
      }
    }
  }
}

// ---------------------------------------------------------------------------
// Generic bf16 MFMA GEMM (m97 128x128 structure).
// MODE 3: bf16 C = acc                              (prep: T-weights, WVW2)
// MODE 4: f32  C = acc + bias[n] + resid[ci]; block-reduced (sum,sumsq)
//              written to part[(pbase+b)*8 + blockIdx.y*2]   (PV' -> y + LN stats)
// MODE 6: f32  C[zslice*sliceE + ci] = acc*scale    (scores, K-split 4, z-packed)
// ---------------------------------------------------------------------------
template<int MODE>
__launch_bounds__(256)
__global__ void gemm_bt(const u16* __restrict__ Ag, int lda, int aRPB, int aRowMax,
                        const u16* __restrict__ Bg, int ldb, int bRPB, int bRowMax,
                        void* __restrict__ Cptr, int ldc, int cRPB, int cRowGuard,
                        const float* __restrict__ bias, const float* __restrict__ resid,
                        int K, float scale, float* __restrict__ part, int pbase,
                        long sliceE) {
  __shared__ __align__(16) u16 As[128 * 64];
  __shared__ __align__(16) u16 Bs[128 * 64];
  const int tid = threadIdx.x;
  const int lane = tid & 63, wid = tid >> 6;
  const int l15 = lane & 15, l4 = lane >> 4;
  const int wr = wid >> 1, wc = wid & 1;
  const int m0 = blockIdx.x * 128, n0 = blockIdx.y * 128;
  int b = blockIdx.z;
  int zslice = 0;
  long koff = 0;
  if (MODE == 6) { zslice = b & 3; koff = (long)zslice * K; b >>= 2; }

  const u16* aSrc[4];
  const u16* bSrc[4];
  u16* aDst[4];
  u16* bDst[4];
#pragma unroll
  for (int i = 0; i < 4; ++i) {
    int c = i * 256 + tid;
    int r = c >> 3, g = c & 7;
    long arow = (long)b * aRPB + m0 + r; if (arow > aRowMax) arow = aRowMax;
    aSrc[i] = Ag + arow * (long)lda + koff + g * 8;
    aDst[i] = &As[c * 8];
    long brow = (long)b * bRPB + n0 + r; if (brow > bRowMax) brow = bRowMax;
    bSrc[i] = Bg + brow * (long)ldb + koff + g * 8;
    bDst[i] = &Bs[c * 8];
  }

  f32x4 acc[4][4];
#pragma unroll
  for (int i = 0; i < 4; ++i)
#pragma unroll
    for (int j = 0; j < 4; ++j) acc[i][j] = (f32x4){0.f, 0.f, 0.f, 0.f};

  for (int kt = 0; kt < K; kt += 64) {
#pragma unroll
    for (int i = 0; i < 4; ++i) gload_lds16(aSrc[i] + kt, aDst[i]);
#pragma unroll
    for (int i = 0; i < 4; ++i) gload_lds16(bSrc[i] + kt, bDst[i]);
    __syncthreads();
#pragma unroll
    for (int kk = 0; kk < 2; ++kk) {
      s16x8 af[4], bfr[4];
#pragma unroll
      for (int mi = 0; mi < 4; ++mi) {
        int rr = wr * 64 + mi * 16 + l15;
        af[mi] = *(const s16x8*)&As[rr * 64 + kk * 32 + l4 * 8];
      }
#pragma unroll
      for (int ni = 0; ni < 4; ++ni) {
        int rr = wc * 64 + ni * 16 + l15;
        bfr[ni] = *(const s16x8*)&Bs[rr * 64 + kk * 32 + l4 * 8];
      }
#pragma unroll
      for (int mi = 0; mi < 4; ++mi)
#pragma unroll
        for (int ni = 0; ni < 4; ++ni)
          acc[mi][ni] = __builtin_amdgcn_mfma_f32_16x16x32_bf16(af[mi], bfr[ni], acc[mi][ni], 0, 0, 0);
    }
    __syncthreads();
  }

  const long cRow0 = (long)b * cRPB + m0;
  float lsum = 0.f, lsq = 0.f;
#pragma unroll
  for (int mi = 0; mi < 4; ++mi) {
#pragma unroll
    for (int ni = 0; ni < 4; ++ni) {
      const int n = n0 + wc * 64 + ni * 16 + l15;
      float bv = 0.f;
      if (MODE == 4) bv = bias[n];
#pragma unroll
      for (int r = 0; r < 4; ++r) {
        const int s = wr * 64 + mi * 16 + l4 * 4 + r;
        if (m0 + s < cRowGuard) {
          const long ci = (cRow0 + s) * (long)ldc + n;
          float v = acc[mi][ni][r];
          if (MODE == 3)      { ((u16*)Cptr)[ci] = f2bf(v); }
          else if (MODE == 6) { ((float*)Cptr)[(long)zslice * sliceE + ci] = v * scale; }
          else                { v += bv + resid[ci]; ((float*)Cptr)[ci] = v;
                                lsum += v; lsq += v * v; }
        }
      }
    }
  }

  if (MODE == 4) {
    float* shs = (float*)As;
    float* shq = (float*)Bs;
    shs[tid] = lsum; shq[tid] = lsq;
    __syncthreads();
    for (int off = 128; off; off >>= 1) {
      if (tid < off) { shs[tid] += shs[tid + off]; shq[tid] += shq[tid + off]; }
      __syncthreads();
    }
    if (tid == 0) {
      part[((long)pbase + b) * 8 + blockIdx.y * 2]     = shs[0];
      part[((long)pbase + b) * 8 + blockIdx.y * 2 + 1] = shq[0];
    }
  }
}

// ---------------------------------------------------------------------------
// Fused softmax (4-slice sum, tril mask) + VW2 transpose, role by block id.
//  blocks [0, CH*32): softmax rows -> P
//  blocks [CH*32, CH*48): transpose TW VW2-section -> VW2T [b][512][128]
// ---------------------------------------------------------------------------
__launch_bounds__(256)
__global__ void softmax_vt(const float* __restrict__ S, u16* __restrict__ P,
                           long sliceE, const u16* __restrict__ TWv,
                           u16* __restrict__ VW2T, int CH) {
  __shared__ __align__(16) u16 t[64][72];
  const int tid = threadIdx.x;
  const int nb_sm = CH * 32;
  if ((int)blockIdx.x < nb_sm) {
    const int wid = tid >> 6, lane = tid & 63;
    const long rowg = (long)blockIdx.x * 4 + wid;
    const int i = (int)(rowg & 127);
    const float* srow = S + rowg * 128;
    u16* prow = P + rowg * 128;
    if (i >= 100) { prow[lane] = 0; prow[lane + 64] = 0; return; }
    const int jmax = (i + 1 < 99) ? i + 1 : 99;        // tril(k=1): j <= i+1, j < 100
    bool v0 = lane <= jmax, v1 = (lane + 64) <= jmax;
    float a0 = srow[lane]              + srow[sliceE + lane] +
               srow[2 * sliceE + lane] + srow[3 * sliceE + lane];
    float a1 = srow[lane + 64]              + srow[sliceE + lane + 64] +
               srow[2 * sliceE + lane + 64] + srow[3 * sliceE + lane + 64];
    float s0 = v0 ? a0 : -3e38f;
    float s1 = v1 ? a1 : -3e38f;
    float m = fmaxf(s0, s1);
#pragma unroll
    for (int off = 32; off; off >>= 1) m = fmaxf(m, __shfl_xor(m, off));
    float e0 = v0 ? __expf(s0 - m) : 0.f;
    float e1 = v1 ? __expf(s1 - m) : 0.f;
    float sum = e0 + e1;
#pragma unroll
    for (int off = 32; off; off >>= 1) sum += __shfl_xor(sum, off);
    float rs = 1.f / sum;
    prow[lane] = f2bf(e0 * rs);
    prow[lane + 64] = f2bf(e1 * rs);
  } else {
    const int vid = (int)blockIdx.x - nb_sm;           // < CH*16
    const int b = vid >> 4, sub = vid & 15;
    const int h0 = (sub & 7) * 64, s0 = (sub >> 3) * 64;
#pragma unroll
    for (int it = 0; it < 2; ++it) {
      int c = it * 256 + tid;
      int s = c >> 3, hh = (c & 7) * 8;
      u16x8 v = {0, 0, 0, 0, 0, 0, 0, 0};
      if (s0 + s < 100) v = *(const u16x8*)&TWv[((long)b * 100 + s0 + s) * 2560 + h0 + hh];
      *(u16x8*)&t[s][hh] = v;
    }
    __syncthreads();
#pragma unroll
    for (int it = 0; it < 2; ++it) {
      int c = it * 256 + tid;
      int h = c >> 3, ss = (c & 7) * 8;
      u16x8 o;
#pragma unroll
      for (int j = 0; j < 8; ++j) o[j] = t[ss + j][h];
      *(u16x8*)&VW2T[((long)b * 512 + h0 + h) * 128 + s0 + ss] = o;
    }
  }
}

// ---------------------------------------------------------------------------
// Merged transpose-cast: blocks [0,256): W_w[512][2048] -> W1t[2048][512]
//                        blocks [256,512): W2_w[2048][512] -> W2t[512][2048]
// ---------------------------------------------------------------------------
__launch_bounds__(256)
__global__ void transpose2_w(const float* __restrict__ Wa, u16* __restrict__ Oa,
                             const float* __restrict__ Wb, u16* __restrict__ Ob) {
  __shared__ __align__(16) float t[64][68];
  const int tid = threadIdx.x;
  int id = blockIdx.x;
  const float* W; u16* Wt; int K, N, n0, k0;
  if (id < 256) { W = Wa; Wt = Oa; K = 512;  N = 2048; n0 = (id & 31) * 64; k0 = (id >> 5) * 64; }
  else { id -= 256; W = Wb; Wt = Ob; K = 2048; N = 512; n0 = (id & 7) * 64; k0 = (id >> 3) * 64; }
#pragma unroll
  for (int it = 0; it < 4; ++it) {
    int c = it * 256 + tid;
    int r = c >> 4, cc = (c & 15) * 4;
    f32x4 v = *(const f32x4*)&W[(long)(k0 + r) * N + n0 + cc];
    *(f32x4*)&t[r][cc] = v;
  }
  __syncthreads();
#pragma unroll
  for (int it = 0; it < 4; ++it) {
    int c = it * 256 + tid;
    int n = c >> 4, kk = (c & 15) * 4;
    u16x4 o;
#pragma unroll
    for (int j = 0; j < 4; ++j) o[j] = f2bf(t[kk + j][n]);
    *(u16x4*)&Wt[(long)(n0 + n) * K + k0 + kk] = o;
  }
}

// ---------------------------------------------------------------------------
// Merged casts: x (3,276,800 f32x4) + WV + WK + WQ (1,048,576 each) -> bf16
// ---------------------------------------------------------------------------
__launch_bounds__(256)
__global__ void cast_all(const float* __restrict__ x, const float* __restrict__ wv,
                         const float* __restrict__ wk, const float* __restrict__ wq,
                         u16* __restrict__ xb, u16* __restrict__ wvb,
                         u16* __restrict__ wkb, u16* __restrict__ wqb) {
  const long NX = 3276800, NW = 1048576, TOT = NX + 3 * NW;
  for (long i = (long)blockIdx.x * 256 + threadIdx.x; i < TOT; i += (long)gridDim.x * 256) {
    const float* in; u16* out; long j;
    if (i < NX)               { in = x;  out = xb;  j = i; }
    else if (i < NX + NW)     { in = wv; out = wvb; j = i - NX; }
    else if (i < NX + 2 * NW) { in = wk; out = wkb; j = i - NX - NW; }
    else                      { in = wq; out = wqb; j = i - NX - 2 * NW; }
    f32x4 v = *(const f32x4*)&in[j * 4];
    u16x4 o;
#pragma unroll
    for (int jj = 0; jj < 4; ++jj) o[jj] = f2bf(v[jj]);
    *(u16x4*)&out[j * 4] = o;
  }
}

// ---------------------------------------------------------------------------
// Merged: blocks [0,2048): bias2[row] = WK_w[row,:] . bQ   (wv fold)
//         blocks [2048,2050): bias2[2048+n] = sum_h bV[h]*W2_w[h][n]
// ---------------------------------------------------------------------------
__launch_bounds__(256)
__global__ void rowdot_bias(const float* __restrict__ WKw, const float* __restrict__ bQ,
                            const float* __restrict__ bV, const float* __restrict__ W2w,
                            float* __restrict__ bias2) {
  const int tid = threadIdx.x;
  if (blockIdx.x < 2048) {
    __shared__ float red[4];
    const float* r = WKw + (long)blockIdx.x * 2048;
    float s = 0.f;
    for (int d = tid; d < 2048; d += 256) s += r[d] * bQ[d];
#pragma unroll
    for (int off = 32; off; off >>= 1) s += __shfl_down(s, off);
    if ((tid & 63) == 0) red[tid >> 6] = s;
    __syncthreads();
    if (tid == 0) bias2[blockIdx.x] = red[0] + red[1] + red[2] + red[3];
  } else {
    int n = (blockIdx.x - 2048) * 256 + tid;   // < 512
    float s = 0.f;
    for (int h = 0; h < 2048; ++h) s += bV[h] * W2w[h * 512 + n];
    bias2[2048 + n] = s;
  }
}

// LN finalize (from per-quadrant partials) + apply, fused
__launch_bounds__(256)
__global__ void ln_apply(float* __restrict__ y, const float* __restrict__ part) {
  const long i4 = (long)blockIdx.x * 256 + threadIdx.x;  // < 3276800
  const int b = (int)(i4 / 12800);
  const float* pb = part + (long)b * 8;
  const float s = pb[0] + pb[2] + pb[4] + pb[6];
  const float q = pb[1] + pb[3] + pb[5] + pb[7];
  const float mean = s * (1.f / 51200.f);
  const float var = q * (1.f / 51200.f) - mean * mean;
  const float rstd = rsqrtf(var + 1e-5f);
  f32x4 v = *(const f32x4*)&y[i4 * 4];
#pragma unroll
  for (int j = 0; j < 4; ++j) v[j] = (v[j] - mean) * rstd;
  *(f32x4*)&y[i4 * 4] = v;
}

extern "C" void kernel_launch(void* const* d_in, const int* in_sizes, int n_in,
                              void* d_out, int out_size, void* d_ws, size_t ws_size,
                              hipStream_t stream) {
  const float* x    = (const float*)d_in[0];
  const float* W_w  = (const float*)d_in[1];
  const float* W_b  = (const float*)d_in[2];
  const float* WK_w = (const float*)d_in[3];
  const float* WK_b = (const float*)d_in[4];
  const float* WQ_w = (const float*)d_in[5];
  const float* WQ_b = (const float*)d_in[6];
  const float* WV_w = (const float*)d_in[7];
  const float* WV_b = (const float*)d_in[8];
  const float* W2_w = (const float*)d_in[9];
  const float* W2_b = (const float*)d_in[10];
  float* out = (float*)d_out;
  const float SC = 0.044194173824159216f;   // 1/sqrt(512)

  // ---- workspace-adaptive batch chunking ----
  const size_t FIXED = 26214400ull + 2097152ull + 10485760ull + 2097152ull +
                       10240ull + 8192ull + 262144ull;
  // per-batch: h 409,600 + TW 512,000 + sc4 262,144 + P 32,768 + VW2T 131,072
  const size_t PERB = 1347584ull;
  const size_t PREPOVL = 25165824ull + 65536ull;  // WVb+WKb+WQb overlay in chunk region
  int CH = 256;
  if (ws_size == 0) CH = 32;
  else {
    while (CH > 4) {
      size_t chunkBytes = (size_t)CH * PERB;
      if (chunkBytes < PREPOVL) chunkBytes = PREPOVL;
      if (FIXED + chunkBytes + 4096 <= ws_size) break;
      CH >>= 1;
    }
  }
  const int NCH = 256 / CH;
  const int CHR = CH * 100;                    // rows per chunk
  const int MT256 = (CHR + 255) / 256;         // 256-tiles per chunk
  const long SLICE = (long)CH * 16384;         // score slice elements

  char* p = (char*)d_ws;
  auto carve = [&](size_t bytes) { char* r = p; p += (bytes + 255) & ~(size_t)255; return r; };
  u16* xb     = (u16*)carve(26214400);                // x bf16 [25600][512]
  u16* W1t    = (u16*)carve(2097152);                 // [2048][512]
  u16* WTt    = (u16*)carve(10485760);                // [2560][2048]  (T | VW2)
  u16* W2t    = (u16*)carve(2097152);                 // [512][2048]
  float* bias2 = (float*)carve(10240);                // [2560] = wv | bV@W2
  float* part = (float*)carve(8192);                  // [256][8] LN partials
  char* chunk0 = p;
  u16* h    = (u16*)carve((size_t)CH * 409600);       // h bf16 [CHR][2048]
  u16* TW   = (u16*)carve((size_t)CH * 512000);       // [CHR][2560] T'|VW2 views
  float* sc = (float*)carve((size_t)CH * 262144);     // scores f32 [4][CH][128][128]
  u16* P    = (u16*)carve((size_t)CH * 32768);        // P bf16 [CH][128][128]
  u16* VW2T = (u16*)carve((size_t)CH * 131072);       // [CH][512][128]
  // prep-only buffers overlay the chunk region (dead before chunk loop starts)
  u16* WVb = (u16*)chunk0;                            // [2048][2048] bf16
  u16* WKb = WVb + 2048 * 2048;
  u16* WQb = WKb + 2048 * 2048;

  // ---- one-time prep (merged launches) ----
  cast_all<<<4096, 256, 0, stream>>>(x, WV_w, WK_w, WQ_w, xb, WVb, WKb, WQb);
  transpose2_w<<<512, 256, 0, stream>>>(W_w, W1t, W2_w, W2t);
  // T-weight Bt rows [0,2048): (WK @ WQ^T)[d2][d1]
  gemm_bt<3><<<dim3(16, 16, 1), 256, 0, stream>>>(WKb, 2048, 0, 2047, WQb, 2048, 0, 2047,
                                                  WTt, 2048, 0, 1 << 30,
                                                  nullptr, nullptr, 2048, 1.f,
                                                  nullptr, 0, 0);
  // VW2 Bt rows [2048,2560): (W2t @ WVb^T)[n][k]
  gemm_bt<3><<<dim3(4, 16, 1), 256, 0, stream>>>(W2t, 2048, 0, 511, WVb, 2048, 0, 2047,
                                                 WTt + (size_t)2048 * 2048, 2048, 0, 1 << 30,
                                                 nullptr, nullptr, 2048, 1.f,
                                                 nullptr, 0, 0);
  // bias2 = [wv = WK_w @ bQ | bV @ W2]  (vv-term folded into T' bias; exact)
  rowdot_bias<<<2050, 256, 0, stream>>>(WK_w, WQ_b, WV_b, W2_w, bias2);

  for (int c = 0; c < NCH; ++c) {
    const u16* xc = xb + (size_t)c * CHR * 512;
    const float* xf = x + (size_t)c * CHR * 512;
    float* outc = out + (size_t)c * CHR * 512;

    // h = relu(xc @ W + b)   M=CHR N=2048 K=512   (256^2, 2-slot, 2 blocks/CU)
    gemm256<1><<<MT256 * 8, 512, 65536, stream>>>(xc, 512, W1t, 512,
                                                  h, 2048, W_b, CHR, 512, 8);
    // [T' | VW2] = h @ [WKWQ^T | WVW2] + (wv|bVW2)   M=CHR N=2560 K=2048
    gemm256<0><<<MT256 * 10, 512, 65536, stream>>>(h, 2048, WTt, 2048,
                                                   TW, 2560, bias2, CHR, 2048, 10);
    // scores[b] = T'[b] @ h[b]^T   K-split 4 -> 4 slices (no atomics, no memset)
    gemm_bt<6><<<dim3(1, 1, CH * 4), 256, 0, stream>>>(TW, 2560, 100, CHR - 1,
                                                       h, 2048, 100, CHR - 1,
                                                       sc, 128, 128, 1 << 30, nullptr, nullptr,
                                                       512, SC, nullptr, 0, SLICE);
    // fused: softmax (blocks [0,CH*32)) + VW2 transpose (blocks [CH*32,CH*48))
    softmax_vt<<<CH * 48, 256, 0, stream>>>(sc, P, SLICE, TW + 2048, VW2T, CH);
    // y = P @ VW2T^T + b2 + x   (f32 out) + LN partial sums per (batch, quadrant)
    gemm_bt<4><<<dim3(1, 4, CH), 256, 0, stream>>>(P, 128, 128, CH * 128 - 1,
                                                   VW2T, 128, 512, CH * 512 - 1,
                                                   outc, 512, 100, 100, W2_b, xf, 128, 1.f,
                                                   part, c * CH, 0);
  }

  ln_apply<<<12800, 256, 0, stream>>>(out, part);
}

// Round 21
// 773.298 us; speedup vs baseline: 1.0069x; 1.0069x over previous
//
#include <hip/hip_runtime.h>
#include <hip/hip_bf16.h>

typedef unsigned int u32;
typedef unsigned short u16;
typedef __attribute__((ext_vector_type(4))) float f32x4;
typedef __attribute__((ext_vector_type(8))) short s16x8;
typedef __attribute__((ext_vector_type(4))) u16 u16x4;
typedef __attribute__((ext_vector_type(8))) u16 u16x8;

#define DEVFN __device__ __forceinline__

DEVFN u16 f2bf(float f) {
  u32 x = __builtin_bit_cast(u32, f);
  u32 r = x + 0x7fffu + ((x >> 16) & 1u);   // round-to-nearest-even
  return (u16)(r >> 16);
}

DEVFN float bf2f(u16 b) { return __builtin_bit_cast(float, (u32)b << 16); }

DEVFN void gload_lds16(const u16* g, u16* l) {
  __builtin_amdgcn_global_load_lds((const __attribute__((address_space(1))) u32*)g,
                                   (__attribute__((address_space(3))) u32*)l, 16, 0, 0);
}

// ===========================================================================
// 256x256-tile 8-wave phase-pipelined bf16 GEMM — BEST-MEASURED FORM (final).
// 152-153us fused GEMM, MfmaUtil 38%, conflicts 0; depth-2 stage-ahead,
// vmcnt(4), one barrier/phase; chunk-XOR swizzle (conflicts 0 since round 5).
// Search ledger: schedule x6 (plateau), fusion x2 (regressed), split-epilogue
// (regressed), occupancy x2 (void/neutral), gaps (harvested), algebra
// (KQV->T fold, vv fold, V@W2 fold). This is the measured optimum.
// ===========================================================================
#define KQV_PHASE(Q, VMWAIT, DOSTAGE)                                          \
  {                                                                            \
    if (DOSTAGE) {                                                             \
      const int g_ = (Q) + 2;                                                  \
      const int sl_ = (g_ & 3) * 8192;                                         \
      const int k0_ = (g_ >> 1) * 64 + (g_ & 1) * 32;                          \
      gload_lds16(aS0 + k0_, smemw + sl_ + ldst);                              \
      gload_lds16(aS1 + k0_, smemw + sl_ + 4096 + ldst);                       \
      gload_lds16(bS0 + k0_, smemw + 32768 + sl_ + ldst);                      \
      gload_lds16(bS1 + k0_, smemw + 32768 + sl_ + 4096 + ldst);               \
    }                                                                          \
    VMWAIT;                                                                    \
    __builtin_amdgcn_s_barrier();                                              \
    {                                                                          \
      const int sl_ = (Q) & 3;                                                 \
      const u16* As_ = smem + sl_ * 8192;                                      \
      const u16* Bs_ = smem + 32768 + sl_ * 8192;                              \
      s16x8 fa_[8], fb_[4];                                                    \
      _Pragma("unroll") for (int mf = 0; mf < 8; ++mf)                         \
          fa_[mf] = *(const s16x8*)(As_ + baseA + mf * 512);                   \
      _Pragma("unroll") for (int nf = 0; nf < 4; ++nf)                         \
          fb_[nf] = *(const s16x8*)(Bs_ + baseB + nf * 512);                   \
      __builtin_amdgcn_s_setprio(1);                                           \
      _Pragma("unroll") for (int mf = 0; mf < 8; ++mf)                         \
        _Pragma("unroll") for (int nf = 0; nf < 4; ++nf)                       \
          acc[mf][nf] = __builtin_amdgcn_mfma_f32_16x16x32_bf16(               \
              fa_[mf], fb_[nf], acc[mf][nf], 0, 0, 0);                         \
      __builtin_amdgcn_s_setprio(0);                                           \
    }                                                                          \
    __builtin_amdgcn_sched_barrier(0);                                         \
  }

#define WAITV4 asm volatile("s_waitcnt vmcnt(4)" ::: "memory")
#define WAITV0 asm volatile("s_waitcnt vmcnt(0)" ::: "memory")
#define WAITNONE ((void)0)

template<int RELU>
__launch_bounds__(512, 2)
__global__ void gemm256(const u16* __restrict__ Ag, int lda,
                        const u16* __restrict__ Bg, int ldb,
                        u16* __restrict__ C, int ldc,
                        const float* __restrict__ bias,
                        int M, int K, int ntiles) {
  extern __shared__ u16 smem_dyn[];
  const u16* smem = smem_dyn;
  u16* smemw = smem_dyn;

  const int tid = threadIdx.x;
  const int lane = tid & 63, wave = tid >> 6;
  const int wm = wave >> 2, wn = wave & 3;          // 2 (M) x 4 (N) waves
  const int l15 = lane & 15, l4 = lane >> 4;

  // bijective XCD-aware swizzle (m204)
  const int nwg = gridDim.x;
  const int q8 = nwg >> 3, r8 = nwg & 7;
  const int xcd = blockIdx.x & 7, io = blockIdx.x >> 3;
  const int wg = (xcd < r8) ? (xcd * (q8 + 1) + io)
                            : (r8 * (q8 + 1) + (xcd - r8) * q8 + io);
  const int m0 = (wg / ntiles) * 256, n0 = (wg % ntiles) * 256;

  const int chunkSwz = (l4 ^ ((l15 >> 1) & 3)) * 8;
  const int baseA = (wm * 128 + l15) * 32 + chunkSwz;
  const int baseB = (wn * 64 + l15) * 32 + chunkSwz;

  const int srow = tid >> 2;
  const int scol = (((tid & 3) ^ ((tid >> 3) & 3))) * 8;
  long ar0 = m0 + srow;        if (ar0 > M - 1) ar0 = M - 1;
  long ar1 = m0 + 128 + srow;  if (ar1 > M - 1) ar1 = M - 1;
  const u16* aS0 = Ag + ar0 * (long)lda + scol;
  const u16* aS1 = Ag + ar1 * (long)lda + scol;
  const u16* bS0 = Bg + (long)(n0 + srow) * ldb + scol;
  const u16* bS1 = Bg + (long)(n0 + 128 + srow) * ldb + scol;
  const int ldst = tid * 8;                       // u16 offset (16B per thread)

  f32x4 acc[8][4];
#pragma unroll
  for (int i = 0; i < 8; ++i)
#pragma unroll
    for (int j = 0; j < 4; ++j) acc[i][j] = (f32x4){0.f, 0.f, 0.f, 0.f};

  const int NT = K >> 6;                          // K-tiles (needs NT>=2)

  // prologue: stage groups 0,1 (slots 0,1)
  {
#pragma unroll
    for (int g_ = 0; g_ < 2; ++g_) {
      const int k0_ = g_ * 32;
      gload_lds16(aS0 + k0_, smemw + g_ * 8192 + ldst);
      gload_lds16(aS1 + k0_, smemw + g_ * 8192 + 4096 + ldst);
      gload_lds16(bS0 + k0_, smemw + 32768 + g_ * 8192 + ldst);
      gload_lds16(bS1 + k0_, smemw + 32768 + g_ * 8192 + 4096 + ldst);
    }
    __builtin_amdgcn_sched_barrier(0);
  }

  for (int t = 0; t < NT - 1; ++t) {
    KQV_PHASE(2 * t,     WAITV4, true);
    KQV_PHASE(2 * t + 1, WAITV4, true);
  }
  KQV_PHASE(2 * NT - 2, WAITV0,   false);
  KQV_PHASE(2 * NT - 1, WAITNONE, false);

  // epilogue: C/D map col=lane&15, row=4*(lane>>4)+reg
#pragma unroll
  for (int mf = 0; mf < 8; ++mf) {
#pragma unroll
    for (int nf = 0; nf < 4; ++nf) {
      const int n = n0 + wn * 64 + nf * 16 + l15;
      const float bv = bias[n];
#pragma unroll
      for (int r = 0; r < 4; ++r) {
        const int s = wm * 128 + mf * 16 + l4 * 4 + r;
        if (m0 + s >= M) continue;
        float v = acc[mf][nf][r] + bv;
        if (RELU) v = v > 0.f ? v : 0.f;
        C[(long)(m0 + s) * ldc + n] = f2bf(v);
      }
    }
  }
}

// ---------------------------------------------------------------------------
// Generic bf16 MFMA GEMM (m97 128x128 structure).
// MODE 3: bf16 C = acc                              (prep: T-weights, WVW2)
// MODE 4: f32  C = acc + bias[n] + resid[ci]; block-reduced (sum,sumsq)
//              written to part[(pbase+b)*8 + blockIdx.y*2]   (PV' -> y + LN stats)
// MODE 6: f32  C[zslice*sliceE + ci] = acc*scale    (scores, K-split 4, z-packed)
// ---------------------------------------------------------------------------
template<int MODE>
__launch_bounds__(256)
__global__ void gemm_bt(const u16* __restrict__ Ag, int lda, int aRPB, int aRowMax,
                        const u16* __restrict__ Bg, int ldb, int bRPB, int bRowMax,
                        void* __restrict__ Cptr, int ldc, int cRPB, int cRowGuard,
                        const float* __restrict__ bias, const float* __restrict__ resid,
                        int K, float scale, float* __restrict__ part, int pbase,
                        long sliceE) {
  __shared__ __align__(16) u16 As[128 * 64];
  __shared__ __align__(16) u16 Bs[128 * 64];
  const int tid = threadIdx.x;
  const int lane = tid & 63, wid = tid >> 6;
  const int l15 = lane & 15, l4 = lane >> 4;
  const int wr = wid >> 1, wc = wid & 1;
  const int m0 = blockIdx.x * 128, n0 = blockIdx.y * 128;
  int b = blockIdx.z;
  int zslice = 0;
  long koff = 0;
  if (MODE == 6) { zslice = b & 3; koff = (long)zslice * K; b >>= 2; }

  const u16* aSrc[4];
  const u16* bSrc[4];
  u16* aDst[4];
  u16* bDst[4];
#pragma unroll
  for (int i = 0; i < 4; ++i) {
    int c = i * 256 + tid;
    int r = c >> 3, g = c & 7;
    long arow = (long)b * aRPB + m0 + r; if (arow > aRowMax) arow = aRowMax;
    aSrc[i] = Ag + arow * (long)lda + koff + g * 8;
    aDst[i] = &As[c * 8];
    long brow = (long)b * bRPB + n0 + r; if (brow > bRowMax) brow = bRowMax;
    bSrc[i] = Bg + brow * (long)ldb + koff + g * 8;
    bDst[i] = &Bs[c * 8];
  }

  f32x4 acc[4][4];
#pragma unroll
  for (int i = 0; i < 4; ++i)
#pragma unroll
    for (int j = 0; j < 4; ++j) acc[i][j] = (f32x4){0.f, 0.f, 0.f, 0.f};

  for (int kt = 0; kt < K; kt += 64) {
#pragma unroll
    for (int i = 0; i < 4; ++i) gload_lds16(aSrc[i] + kt, aDst[i]);
#pragma unroll
    for (int i = 0; i < 4; ++i) gload_lds16(bSrc[i] + kt, bDst[i]);
    __syncthreads();
#pragma unroll
    for (int kk = 0; kk < 2; ++kk) {
      s16x8 af[4], bfr[4];
#pragma unroll
      for (int mi = 0; mi < 4; ++mi) {
        int rr = wr * 64 + mi * 16 + l15;
        af[mi] = *(const s16x8*)&As[rr * 64 + kk * 32 + l4 * 8];
      }
#pragma unroll
      for (int ni = 0; ni < 4; ++ni) {
        int rr = wc * 64 + ni * 16 + l15;
        bfr[ni] = *(const s16x8*)&Bs[rr * 64 + kk * 32 + l4 * 8];
      }
#pragma unroll
      for (int mi = 0; mi < 4; ++mi)
#pragma unroll
        for (int ni = 0; ni < 4; ++ni)
          acc[mi][ni] = __builtin_amdgcn_mfma_f32_16x16x32_bf16(af[mi], bfr[ni], acc[mi][ni], 0, 0, 0);
    }
    __syncthreads();
  }

  const long cRow0 = (long)b * cRPB + m0;
  float lsum = 0.f, lsq = 0.f;
#pragma unroll
  for (int mi = 0; mi < 4; ++mi) {
#pragma unroll
    for (int ni = 0; ni < 4; ++ni) {
      const int n = n0 + wc * 64 + ni * 16 + l15;
      float bv = 0.f;
      if (MODE == 4) bv = bias[n];
#pragma unroll
      for (int r = 0; r < 4; ++r) {
        const int s = wr * 64 + mi * 16 + l4 * 4 + r;
        if (m0 + s < cRowGuard) {
          const long ci = (cRow0 + s) * (long)ldc + n;
          float v = acc[mi][ni][r];
          if (MODE == 3)      { ((u16*)Cptr)[ci] = f2bf(v); }
          else if (MODE == 6) { ((float*)Cptr)[(long)zslice * sliceE + ci] = v * scale; }
          else                { v += bv + resid[ci]; ((float*)Cptr)[ci] = v;
                                lsum += v; lsq += v * v; }
        }
      }
    }
  }

  if (MODE == 4) {
    float* shs = (float*)As;
    float* shq = (float*)Bs;
    shs[tid] = lsum; shq[tid] = lsq;
    __syncthreads();
    for (int off = 128; off; off >>= 1) {
      if (tid < off) { shs[tid] += shs[tid + off]; shq[tid] += shq[tid + off]; }
      __syncthreads();
    }
    if (tid == 0) {
      part[((long)pbase + b) * 8 + blockIdx.y * 2]     = shs[0];
      part[((long)pbase + b) * 8 + blockIdx.y * 2 + 1] = shq[0];
    }
  }
}

// ---------------------------------------------------------------------------
// Fused softmax (4-slice sum, tril mask) + VW2 transpose, role by block id.
//  blocks [0, CH*32): softmax rows -> P
//  blocks [CH*32, CH*48): transpose TW VW2-section -> VW2T [b][512][128]
// ---------------------------------------------------------------------------
__launch_bounds__(256)
__global__ void softmax_vt(const float* __restrict__ S, u16* __restrict__ P,
                           long sliceE, const u16* __restrict__ TWv,
                           u16* __restrict__ VW2T, int CH) {
  __shared__ __align__(16) u16 t[64][72];
  const int tid = threadIdx.x;
  const int nb_sm = CH * 32;
  if ((int)blockIdx.x < nb_sm) {
    const int wid = tid >> 6, lane = tid & 63;
    const long rowg = (long)blockIdx.x * 4 + wid;
    const int i = (int)(rowg & 127);
    const float* srow = S + rowg * 128;
    u16* prow = P + rowg * 128;
    if (i >= 100) { prow[lane] = 0; prow[lane + 64] = 0; return; }
    const int jmax = (i + 1 < 99) ? i + 1 : 99;        // tril(k=1): j <= i+1, j < 100
    bool v0 = lane <= jmax, v1 = (lane + 64) <= jmax;
    float a0 = srow[lane]              + srow[sliceE + lane] +
               srow[2 * sliceE + lane] + srow[3 * sliceE + lane];
    float a1 = srow[lane + 64]              + srow[sliceE + lane + 64] +
               srow[2 * sliceE + lane + 64] + srow[3 * sliceE + lane + 64];
    float s0 = v0 ? a0 : -3e38f;
    float s1 = v1 ? a1 : -3e38f;
    float m = fmaxf(s0, s1);
#pragma unroll
    for (int off = 32; off; off >>= 1) m = fmaxf(m, __shfl_xor(m, off));
    float e0 = v0 ? __expf(s0 - m) : 0.f;
    float e1 = v1 ? __expf(s1 - m) : 0.f;
    float sum = e0 + e1;
#pragma unroll
    for (int off = 32; off; off >>= 1) sum += __shfl_xor(sum, off);
    float rs = 1.f / sum;
    prow[lane] = f2bf(e0 * rs);
    prow[lane + 64] = f2bf(e1 * rs);
  } else {
    const int vid = (int)blockIdx.x - nb_sm;           // < CH*16
    const int b = vid >> 4, sub = vid & 15;
    const int h0 = (sub & 7) * 64, s0 = (sub >> 3) * 64;
#pragma unroll
    for (int it = 0; it < 2; ++it) {
      int c = it * 256 + tid;
      int s = c >> 3, hh = (c & 7) * 8;
      u16x8 v = {0, 0, 0, 0, 0, 0, 0, 0};
      if (s0 + s < 100) v = *(const u16x8*)&TWv[((long)b * 100 + s0 + s) * 2560 + h0 + hh];
      *(u16x8*)&t[s][hh] = v;
    }
    __syncthreads();
#pragma unroll
    for (int it = 0; it < 2; ++it) {
      int c = it * 256 + tid;
      int h = c >> 3, ss = (c & 7) * 8;
      u16x8 o;
#pragma unroll
      for (int j = 0; j < 8; ++j) o[j] = t[ss + j][h];
      *(u16x8*)&VW2T[((long)b * 512 + h0 + h) * 128 + s0 + ss] = o;
    }
  }
}

// ---------------------------------------------------------------------------
// Merged transpose-cast: blocks [0,256): W_w[512][2048] -> W1t[2048][512]
//                        blocks [256,512): W2_w[2048][512] -> W2t[512][2048]
// ---------------------------------------------------------------------------
__launch_bounds__(256)
__global__ void transpose2_w(const float* __restrict__ Wa, u16* __restrict__ Oa,
                             const float* __restrict__ Wb, u16* __restrict__ Ob) {
  __shared__ __align__(16) float t[64][68];
  const int tid = threadIdx.x;
  int id = blockIdx.x;
  const float* W; u16* Wt; int K, N, n0, k0;
  if (id < 256) { W = Wa; Wt = Oa; K = 512;  N = 2048; n0 = (id & 31) * 64; k0 = (id >> 5) * 64; }
  else { id -= 256; W = Wb; Wt = Ob; K = 2048; N = 512; n0 = (id & 7) * 64; k0 = (id >> 3) * 64; }
#pragma unroll
  for (int it = 0; it < 4; ++it) {
    int c = it * 256 + tid;
    int r = c >> 4, cc = (c & 15) * 4;
    f32x4 v = *(const f32x4*)&W[(long)(k0 + r) * N + n0 + cc];
    *(f32x4*)&t[r][cc] = v;
  }
  __syncthreads();
#pragma unroll
  for (int it = 0; it < 4; ++it) {
    int c = it * 256 + tid;
    int n = c >> 4, kk = (c & 15) * 4;
    u16x4 o;
#pragma unroll
    for (int j = 0; j < 4; ++j) o[j] = f2bf(t[kk + j][n]);
    *(u16x4*)&Wt[(long)(n0 + n) * K + k0 + kk] = o;
  }
}

// ---------------------------------------------------------------------------
// Merged casts: x (3,276,800 f32x4) + WV + WK + WQ (1,048,576 each) -> bf16
// ---------------------------------------------------------------------------
__launch_bounds__(256)
__global__ void cast_all(const float* __restrict__ x, const float* __restrict__ wv,
                         const float* __restrict__ wk, const float* __restrict__ wq,
                         u16* __restrict__ xb, u16* __restrict__ wvb,
                         u16* __restrict__ wkb, u16* __restrict__ wqb) {
  const long NX = 3276800, NW = 1048576, TOT = NX + 3 * NW;
  for (long i = (long)blockIdx.x * 256 + threadIdx.x; i < TOT; i += (long)gridDim.x * 256) {
    const float* in; u16* out; long j;
    if (i < NX)               { in = x;  out = xb;  j = i; }
    else if (i < NX + NW)     { in = wv; out = wvb; j = i - NX; }
    else if (i < NX + 2 * NW) { in = wk; out = wkb; j = i - NX - NW; }
    else                      { in = wq; out = wqb; j = i - NX - 2 * NW; }
    f32x4 v = *(const f32x4*)&in[j * 4];
    u16x4 o;
#pragma unroll
    for (int jj = 0; jj < 4; ++jj) o[jj] = f2bf(v[jj]);
    *(u16x4*)&out[j * 4] = o;
  }
}

// ---------------------------------------------------------------------------
// Merged: blocks [0,2048): bias2[row] = WK_w[row,:] . bQ   (wv fold)
//         blocks [2048,2050): bias2[2048+n] = sum_h bV[h]*W2_w[h][n]
// ---------------------------------------------------------------------------
__launch_bounds__(256)
__global__ void rowdot_bias(const float* __restrict__ WKw, const float* __restrict__ bQ,
                            const float* __restrict__ bV, const float* __restrict__ W2w,
                            float* __restrict__ bias2) {
  const int tid = threadIdx.x;
  if (blockIdx.x < 2048) {
    __shared__ float red[4];
    const float* r = WKw + (long)blockIdx.x * 2048;
    float s = 0.f;
    for (int d = tid; d < 2048; d += 256) s += r[d] * bQ[d];
#pragma unroll
    for (int off = 32; off; off >>= 1) s += __shfl_down(s, off);
    if ((tid & 63) == 0) red[tid >> 6] = s;
    __syncthreads();
    if (tid == 0) bias2[blockIdx.x] = red[0] + red[1] + red[2] + red[3];
  } else {
    int n = (blockIdx.x - 2048) * 256 + tid;   // < 512
    float s = 0.f;
    for (int h = 0; h < 2048; ++h) s += bV[h] * W2w[h * 512 + n];
    bias2[2048 + n] = s;
  }
}

// LN finalize (from per-quadrant partials) + apply, fused
__launch_bounds__(256)
__global__ void ln_apply(float* __restrict__ y, const float* __restrict__ part) {
  const long i4 = (long)blockIdx.x * 256 + threadIdx.x;  // < 3276800
  const int b = (int)(i4 / 12800);
  const float* pb = part + (long)b * 8;
  const float s = pb[0] + pb[2] + pb[4] + pb[6];
  const float q = pb[1] + pb[3] + pb[5] + pb[7];
  const float mean = s * (1.f / 51200.f);
  const float var = q * (1.f / 51200.f) - mean * mean;
  const float rstd = rsqrtf(var + 1e-5f);
  f32x4 v = *(const f32x4*)&y[i4 * 4];
#pragma unroll
  for (int j = 0; j < 4; ++j) v[j] = (v[j] - mean) * rstd;
  *(f32x4*)&y[i4 * 4] = v;
}

extern "C" void kernel_launch(void* const* d_in, const int* in_sizes, int n_in,
                              void* d_out, int out_size, void* d_ws, size_t ws_size,
                              hipStream_t stream) {
  const float* x    = (const float*)d_in[0];
  const float* W_w  = (const float*)d_in[1];
  const float* W_b  = (const float*)d_in[2];
  const float* WK_w = (const float*)d_in[3];
  const float* WK_b = (const float*)d_in[4];
  const float* WQ_w = (const float*)d_in[5];
  const float* WQ_b = (const float*)d_in[6];
  const float* WV_w = (const float*)d_in[7];
  const float* WV_b = (const float*)d_in[8];
  const float* W2_w = (const float*)d_in[9];
  const float* W2_b = (const float*)d_in[10];
  float* out = (float*)d_out;
  const float SC = 0.044194173824159216f;   // 1/sqrt(512)

  // ---- workspace-adaptive batch chunking ----
  const size_t FIXED = 26214400ull + 2097152ull + 10485760ull + 2097152ull +
                       10240ull + 8192ull + 262144ull;
  // per-batch: h 409,600 + TW 512,000 + sc4 262,144 + P 32,768 + VW2T 131,072
  const size_t PERB = 1347584ull;
  const size_t PREPOVL = 25165824ull + 65536ull;  // WVb+WKb+WQb overlay in chunk region
  int CH = 256;
  if (ws_size == 0) CH = 32;
  else {
    while (CH > 4) {
      size_t chunkBytes = (size_t)CH * PERB;
      if (chunkBytes < PREPOVL) chunkBytes = PREPOVL;
      if (FIXED + chunkBytes + 4096 <= ws_size) break;
      CH >>= 1;
    }
  }
  const int NCH = 256 / CH;
  const int CHR = CH * 100;                    // rows per chunk
  const int MT256 = (CHR + 255) / 256;         // 256-tiles per chunk
  const long SLICE = (long)CH * 16384;         // score slice elements

  char* p = (char*)d_ws;
  auto carve = [&](size_t bytes) { char* r = p; p += (bytes + 255) & ~(size_t)255; return r; };
  u16* xb     = (u16*)carve(26214400);                // x bf16 [25600][512]
  u16* W1t    = (u16*)carve(2097152);                 // [2048][512]
  u16* WTt    = (u16*)carve(10485760);                // [2560][2048]  (T | VW2)
  u16* W2t    = (u16*)carve(2097152);                 // [512][2048]
  float* bias2 = (float*)carve(10240);                // [2560] = wv | bV@W2
  float* part = (float*)carve(8192);                  // [256][8] LN partials
  char* chunk0 = p;
  u16* h    = (u16*)carve((size_t)CH * 409600);       // h bf16 [CHR][2048]
  u16* TW   = (u16*)carve((size_t)CH * 512000);       // [CHR][2560] T'|VW2 views
  float* sc = (float*)carve((size_t)CH * 262144);     // scores f32 [4][CH][128][128]
  u16* P    = (u16*)carve((size_t)CH * 32768);        // P bf16 [CH][128][128]
  u16* VW2T = (u16*)carve((size_t)CH * 131072);       // [CH][512][128]
  // prep-only buffers overlay the chunk region (dead before chunk loop starts)
  u16* WVb = (u16*)chunk0;                            // [2048][2048] bf16
  u16* WKb = WVb + 2048 * 2048;
  u16* WQb = WKb + 2048 * 2048;

  // ---- one-time prep (merged launches) ----
  cast_all<<<4096, 256, 0, stream>>>(x, WV_w, WK_w, WQ_w, xb, WVb, WKb, WQb);
  transpose2_w<<<512, 256, 0, stream>>>(W_w, W1t, W2_w, W2t);
  // T-weight Bt rows [0,2048): (WK @ WQ^T)[d2][d1]
  gemm_bt<3><<<dim3(16, 16, 1), 256, 0, stream>>>(WKb, 2048, 0, 2047, WQb, 2048, 0, 2047,
                                                  WTt, 2048, 0, 1 << 30,
                                                  nullptr, nullptr, 2048, 1.f,
                                                  nullptr, 0, 0);
  // VW2 Bt rows [2048,2560): (W2t @ WVb^T)[n][k]
  gemm_bt<3><<<dim3(4, 16, 1), 256, 0, stream>>>(W2t, 2048, 0, 511, WVb, 2048, 0, 2047,
                                                 WTt + (size_t)2048 * 2048, 2048, 0, 1 << 30,
                                                 nullptr, nullptr, 2048, 1.f,
                                                 nullptr, 0, 0);
  // bias2 = [wv = WK_w @ bQ | bV @ W2]  (vv-term folded into T' bias; exact)
  rowdot_bias<<<2050, 256, 0, stream>>>(WK_w, WQ_b, WV_b, W2_w, bias2);

  for (int c = 0; c < NCH; ++c) {
    const u16* xc = xb + (size_t)c * CHR * 512;
    const float* xf = x + (size_t)c * CHR * 512;
    float* outc = out + (size_t)c * CHR * 512;

    // h = relu(xc @ W + b)   M=CHR N=2048 K=512   (256^2 pipeline, relu epilogue)
    gemm256<1><<<MT256 * 8, 512, 131072, stream>>>(xc, 512, W1t, 512,
                                                   h, 2048, W_b, CHR, 512, 8);
    // [T' | VW2] = h @ [WKWQ^T | WVW2] + (wv|bVW2)   M=CHR N=2560 K=2048
    gemm256<0><<<MT256 * 10, 512, 131072, stream>>>(h, 2048, WTt, 2048,
                                                    TW, 2560, bias2, CHR, 2048, 10);
    // scores[b] = T'[b] @ h[b]^T   K-split 4 -> 4 slices (no atomics, no memset)
    gemm_bt<6><<<dim3(1, 1, CH * 4), 256, 0, stream>>>(TW, 2560, 100, CHR - 1,
                                                       h, 2048, 100, CHR - 1,
                                                       sc, 128, 128, 1 << 30, nullptr, nullptr,
                                                       512, SC, nullptr, 0, SLICE);
    // fused: softmax (blocks [0,CH*32)) + VW2 transpose (blocks [CH*32,CH*48))
    softmax_vt<<<CH * 48, 256, 0, stream>>>(sc, P, SLICE, TW + 2048, VW2T, CH);
    // y = P @ VW2T^T + b2 + x   (f32 out) + LN partial sums per (batch, quadrant)
    gemm_bt<4><<<dim3(1, 4, CH), 256, 0, stream>>>(P, 128, 128, CH * 128 - 1,
                                                   VW2T, 128, 512, CH * 512 - 1,
                                                   outc, 512, 100, 100, W2_b, xf, 128, 1.f,
                                                   part, c * CH, 0);
  }

  ln_apply<<<12800, 256, 0, stream>>>(out, part);
}